// Round 15
// baseline (357.691 us; speedup 1.0000x reference)
//
#include <hip/hip_runtime.h>

// Problem constants
constexpr int CIN   = 256;   // feature channels
constexpr int KD    = 32;    // key dim
constexpr int VD    = 128;   // value dim
constexpr int NCLS  = 10;
constexpr int BS    = 4;
constexpr int HW    = 256;   // 16*16
constexpr float BNC = 0.9999950000374997f; // 1/sqrt(1+1e-5)

typedef unsigned short u16;
typedef __attribute__((ext_vector_type(8))) __bf16 bf8v;
typedef __attribute__((ext_vector_type(4))) float f4v;

static __device__ __forceinline__ int imin(int a, int b) { return a < b ? a : b; }

static __device__ __forceinline__ u16 f2bf(float v) {
  union { float f; unsigned u; } x; x.f = v;
  unsigned r = x.u + 0x7FFFu + ((x.u >> 16) & 1u);
  return (u16)(r >> 16);
}
static __device__ __forceinline__ float bf2f(u16 h) {
  union { unsigned u; float f; } x; x.u = ((unsigned)h) << 16;
  return x.f;
}

static __device__ __forceinline__ f4v mfma16(bf8v a, bf8v b, f4v c) {
  return __builtin_amdgcn_mfma_f32_16x16x32_bf16(a, b, c, 0, 0, 0);
}

__constant__ const int c_jbase[5] = {0, 16384, 20480, 21504, 21760};

// ---------------------------------------------------------------------------
// Merged independent preps (unchanged from r14).
__global__ __launch_bounds__(256) void k_prep1(
    const float* __restrict__ f0, const float* __restrict__ f1,
    const float* __restrict__ f2, const float* __restrict__ f3,
    const float* __restrict__ f4, const float* __restrict__ att,
    const float* __restrict__ vqw, const float* __restrict__ vtw,
    const float* __restrict__ kqw, const float* __restrict__ ktw,
    const float* __restrict__ cw, const float* __restrict__ gamma,
    const float* __restrict__ cbias, const float* __restrict__ beta,
    u16* __restrict__ Xf, u16* __restrict__ Xr,
    u16* __restrict__ Awv, u16* __restrict__ Awk,
    u16* __restrict__ cwA, u16* __restrict__ cw2A, float* __restrict__ cb) {
  __shared__ float sm[16][65];
  int blk = blockIdx.x;
  int tid = threadIdx.x;
  if (blk < 384) {
    const float* fin; u16* dstbase; int SS, px0;
    if (blk < 344) {
      int l, base, nb;
      if (blk < 256)      { l = 0; base = 0;   nb = 64; }
      else if (blk < 320) { l = 1; base = 256; nb = 16; }
      else if (blk < 336) { l = 2; base = 320; nb = 4; }
      else if (blk < 340) { l = 3; base = 336; nb = 1; }
      else                { l = 4; base = 340; nb = 1; }
      int local = blk - base;
      int b = local / nb, chunk = local % nb;
      int S = 64 >> l; SS = S * S;
      px0 = chunk * 64;
      fin = (l == 0 ? f0 : l == 1 ? f1 : l == 2 ? f2 : l == 3 ? f3 : f4)
            + (size_t)b * CIN * SS;
      dstbase = Xf + (size_t)(c_jbase[l] + b * SS) * 512;
    } else {
      int a = blk - 344;
      int imgA = a >> 2, chunk = a & 3;
      SS = 256; px0 = chunk * 64;
      fin = att + (size_t)imgA * CIN * 256;
      dstbase = Xr + (size_t)(20 + imgA) * 131072;
    }
    int px_r = tid & 63, cr = tid >> 6;
    int px_w = tid >> 2, c4 = (tid & 3) * 4;
    for (int cbk = 0; cbk < 16; ++cbk) {
      __syncthreads();
#pragma unroll
      for (int q = 0; q < 4; ++q) {
        int cl = q * 4 + cr;
        float v = 0.f;
        if (px0 + px_r < SS) v = fin[(size_t)(cbk * 16 + cl) * SS + px0 + px_r];
        sm[cl][px_r] = v;
      }
      __syncthreads();
      if (px0 + px_w < SS) {
        u16 hh[4], ll[4];
#pragma unroll
        for (int e = 0; e < 4; ++e) {
          float v = sm[c4 + e][px_w];
          hh[e] = f2bf(v); ll[e] = f2bf(v - bf2f(hh[e]));
        }
        uint2 wh, wl;
        wh.x = (unsigned)hh[0] | ((unsigned)hh[1] << 16); wh.y = (unsigned)hh[2] | ((unsigned)hh[3] << 16);
        wl.x = (unsigned)ll[0] | ((unsigned)ll[1] << 16); wl.y = (unsigned)ll[2] | ((unsigned)ll[3] << 16);
        u16* dst = dstbase + (size_t)(px0 + px_w) * 512 + cbk * 16 + c4;
        *reinterpret_cast<uint2*>(dst) = wh;
        *reinterpret_cast<uint2*>(dst + 256) = wl;
      }
    }
  } else if (blk < 1464) {
    int gid = (blk - 384) * 256 + tid;
    int lane = gid & 63;
    int grp = gid >> 6;
    const float* src; u16* dst; int kc;
    if (grp < 3456) {
      kc = grp % 72; int ot = (grp / 72) % 8; int sid = grp / (72 * 8);
      src = (sid < 5 ? vqw + (size_t)sid * VD * 2304 : vtw) + (size_t)(ot * 16 + (lane & 15)) * 2304;
      dst = Awv + (size_t)grp * 1024;
    } else {
      int g2 = grp - 3456;
      kc = g2 % 72; int ot = (g2 / 72) % 2; int sid = g2 / 144;
      src = (sid < 5 ? kqw + (size_t)sid * KD * 2304 : ktw) + (size_t)(ot * 16 + (lane & 15)) * 2304;
      dst = Awk + (size_t)g2 * 1024;
    }
    int q0 = (lane >> 4) * 8;
    int t = kc >> 3, c0 = (kc & 7) * 32;
#pragma unroll
    for (int i = 0; i < 8; ++i) {
      int c = c0 + q0 + i;
      float v = src[c * 9 + t];
      u16 h = f2bf(v);
      dst[lane * 8 + i] = h;
      dst[512 + lane * 8 + i] = f2bf(v - bf2f(h));
    }
  } else if (blk < 1848) {
    int blk2 = blk - 1464;
    if (blk2 < 64) {
      int gid = blk2 * 256 + tid;
      int oc = gid >> 6, c0 = (gid & 63) * 4;
      float4 v = *reinterpret_cast<const float4*>(cw + (size_t)oc * 512 + c0);
      const float* vv = (const float*)&v;
      u16 h[4], l[4];
#pragma unroll
      for (int e = 0; e < 4; ++e) { h[e] = f2bf(vv[e]); l[e] = f2bf(vv[e] - bf2f(h[e])); }
      uint2 wh, wl;
      wh.x = (unsigned)h[0] | ((unsigned)h[1] << 16); wh.y = (unsigned)h[2] | ((unsigned)h[3] << 16);
      wl.x = (unsigned)l[0] | ((unsigned)l[1] << 16); wl.y = (unsigned)l[2] | ((unsigned)l[3] << 16);
      *reinterpret_cast<uint2*>(cwA + (size_t)oc * 256 + c0) = wh;
      *reinterpret_cast<uint2*>(cwA + 65536 + (size_t)oc * 256 + c0) = wl;
    } else {
      int gid = (blk2 - 64) * 256 + tid;
      int l = gid / 16384, rem = gid % 16384;
      int oc = rem >> 6, c0 = (rem & 63) * 4;
      u16 h[4], lo[4];
#pragma unroll
      for (int e = 0; e < 4; ++e) {
        int c = c0 + e;
        float v = cw[(size_t)oc * 512 + 256 + c] * (gamma[l * 256 + c] * BNC);
        h[e] = f2bf(v); lo[e] = f2bf(v - bf2f(h[e]));
      }
      uint2 wh, wl;
      wh.x = (unsigned)h[0] | ((unsigned)h[1] << 16); wh.y = (unsigned)h[2] | ((unsigned)h[3] << 16);
      wl.x = (unsigned)lo[0] | ((unsigned)lo[1] << 16); wl.y = (unsigned)lo[2] | ((unsigned)lo[3] << 16);
      *reinterpret_cast<uint2*>(cw2A + (size_t)l * 65536 + oc * 256 + c0) = wh;
      *reinterpret_cast<uint2*>(cw2A + 327680 + (size_t)l * 65536 + oc * 256 + c0) = wl;
    }
  } else {
    int l = blk - 1848, oc = tid;
    float s = cbias[oc];
    for (int c = 0; c < CIN; ++c)
      s += cw[(size_t)oc * 512 + 256 + c] * beta[l * CIN + c];
    cb[l * CIN + oc] = s;
  }
}

// ---------------------------------------------------------------------------
// Level imgs: bilinear-resize Xf rows -> Xr[img][px][2][256]. grid = 320.
__global__ __launch_bounds__(256) void k_prep_xr(
    const u16* __restrict__ Xf, u16* __restrict__ Xr, u16* __restrict__ zrow) {
  int blk = blockIdx.x;
  int img = blk >> 4, yr = blk & 15;
  int l = img >> 2, b = img & 3;
  int S = 64 >> l, SS = S * S;
  int c = threadIdx.x;
  if (blk == 0) { zrow[c] = 0; zrow[256 + c] = 0; }
  float cyf = (float)(yr * (S - 1)) / 15.0f;
  int ylo = imin((int)cyf, S - 2); float fy = cyf - (float)ylo;
  u16* dst = Xr + ((size_t)img * 256 + yr * 16) * 512;
  const u16* srcb = Xf + (size_t)(c_jbase[l] + b * SS) * 512;
  for (int x = 0; x < 16; ++x) {
    float cxf = (float)(x * (S - 1)) / 15.0f;
    int xlo = imin((int)cxf, S - 2); float fx = cxf - (float)xlo;
    const u16* r00 = srcb + (size_t)(ylo * S + xlo) * 512;
    const u16* r10 = srcb + (size_t)((ylo + 1) * S + xlo) * 512;
    float v00 = bf2f(r00[c]) + bf2f(r00[256 + c]);
    float v01 = bf2f(r00[512 + c]) + bf2f(r00[768 + c]);
    float v10 = bf2f(r10[c]) + bf2f(r10[256 + c]);
    float v11 = bf2f(r10[512 + c]) + bf2f(r10[768 + c]);
    float v = (1.f - fy) * ((1.f - fx) * v00 + fx * v01)
            + fy * ((1.f - fx) * v10 + fx * v11);
    u16 h = f2bf(v);
    dst[x * 512 + c] = h;
    dst[x * 512 + 256 + c] = f2bf(v - bf2f(h));
  }
}

// ---------------------------------------------------------------------------
// MFMA conv from Xr (unchanged from r14).
__global__ __launch_bounds__(256) void k_conv_mfma(
    const u16* __restrict__ Xr, const u16* __restrict__ Awv, const u16* __restrict__ Awk,
    const u16* __restrict__ zrow,
    float* __restrict__ kqall, u16* __restrict__ vt2, float* __restrict__ f16v,
    const float* __restrict__ vqb, const float* __restrict__ vtb,
    const float* __restrict__ kqb, const float* __restrict__ ktb) {
  int wid = blockIdx.x * 4 + (threadIdx.x >> 6);
  int lane = threadIdx.x & 63;
  bool isV = wid < 1920;
  int img, ot, yp;
  if (isV) { img = wid >> 6; int r = wid & 63; ot = r >> 3; yp = r & 7; }
  else     { int j = wid - 1920; img = j >> 4; int r = j & 15; ot = r >> 3; yp = r & 7; }
  int wset = img < 20 ? (img >> 2) : 5;

  const u16* Ab = isV ? Awv + ((size_t)(wset * 8 + ot)) * 72 * 1024
                      : Awk + ((size_t)(wset * 2 + ot)) * 72 * 1024;
  const u16* Xb = Xr + (size_t)img * 131072;
  int xcol = lane & 15, kg = lane >> 4;
  int y0 = yp * 2, y1 = y0 + 1;

  f4v acc0 = {0.f, 0.f, 0.f, 0.f}, acc1 = {0.f, 0.f, 0.f, 0.f};
  for (int t = 0; t < 9; ++t) {
    int dy = (t >= 6) ? 2 : (t >= 3 ? 1 : 0);
    int dx = t - dy * 3;
    int yy0 = y0 + dy - 1, yy1 = yy0 + 1;
    int xx = xcol + dx - 1;
    bool xok = (unsigned)xx < 16u;
    const u16* base0 = (xok && (unsigned)yy0 < 16u)
                       ? Xb + (size_t)(yy0 * 16 + xx) * 512 : zrow;
    const u16* base1 = (xok && (unsigned)yy1 < 16u)
                       ? Xb + (size_t)(yy1 * 16 + xx) * 512 : zrow;
    const u16* Xr0 = base0 + kg * 8;
    const u16* Xr1 = base1 + kg * 8;
    const u16* Ak = Ab + (size_t)t * 8 * 1024 + lane * 8;
#pragma unroll
    for (int cc = 0; cc < 8; ++cc) {
      bf8v ah = *reinterpret_cast<const bf8v*>(Ak + cc * 1024);
      bf8v al = *reinterpret_cast<const bf8v*>(Ak + cc * 1024 + 512);
      bf8v bh0 = *reinterpret_cast<const bf8v*>(Xr0 + cc * 32);
      bf8v bl0 = *reinterpret_cast<const bf8v*>(Xr0 + cc * 32 + 256);
      bf8v bh1 = *reinterpret_cast<const bf8v*>(Xr1 + cc * 32);
      bf8v bl1 = *reinterpret_cast<const bf8v*>(Xr1 + cc * 32 + 256);
      acc0 = mfma16(ah, bh0, acc0);
      acc0 = mfma16(ah, bl0, acc0);
      acc0 = mfma16(al, bh0, acc0);
      acc1 = mfma16(ah, bh1, acc1);
      acc1 = mfma16(ah, bl1, acc1);
      acc1 = mfma16(al, bh1, acc1);
    }
  }

  int ocbase = ot * 16;
  if (isV && img >= 20) {
    int n = img - 20;
    u16* d2 = vt2 + ((size_t)n * VD + ocbase) * HW;
#pragma unroll
    for (int i = 0; i < 4; ++i) {
      int ocl = kg * 4 + i;
      float bv = vtb[ocbase + ocl];
      float va = acc0[i] + bv, vb = acc1[i] + bv;
      u16 ha = f2bf(va), hb = f2bf(vb);
      size_t ia = (size_t)ocl * HW + y0 * 16 + xcol;
      size_t ib = (size_t)ocl * HW + y1 * 16 + xcol;
      d2[ia] = ha; d2[ia + 327680] = f2bf(va - bf2f(ha));
      d2[ib] = hb; d2[ib + 327680] = f2bf(vb - bf2f(hb));
    }
    return;
  }
  float scale = 1.f;
  const float* bias;
  float* dst;
  if (isV) { dst = f16v + ((size_t)img * VD + ocbase) * HW; bias = vqb + wset * VD + ocbase; scale = (float)NCLS; }
  else if (img < 20) { dst = kqall + ((size_t)img * KD + ocbase) * HW; bias = kqb + wset * KD + ocbase; }
  else { dst = kqall + (size_t)20 * KD * HW + ((size_t)(img - 20) * KD + ocbase) * HW; bias = ktb + ocbase; }
#pragma unroll
  for (int i = 0; i < 4; ++i) {
    int ocl = kg * 4 + i;
    float bv = bias[ocl];
    dst[(size_t)ocl * HW + y0 * 16 + xcol] = (acc0[i] + bv) * scale;
    dst[(size_t)ocl * HW + y1 * 16 + xcol] = (acc1[i] + bv) * scale;
  }
}

// ---------------------------------------------------------------------------
// PAGG: block = (l, bn, jt of 32 j): QK^T -> softmax -> p (LDS fp32 + pT bf16)
// -> aggn MFMA. grid = 1600 x 256. No fa work (split into k_fa2).
__global__ __launch_bounds__(256) void k_pagg(
    const float* __restrict__ kqall, const u16* __restrict__ vt2,
    u16* __restrict__ pT, float* __restrict__ aggn) {
  int blk = blockIdx.x;
  int l = blk / 320;
  int g = blk % 320;
  int bn = g >> 3, jt = g & 7;
  int b = bn / NCLS, n = bn % NCLS;
  int t = threadIdx.x;
  int iq = t >> 5, jl = t & 31;
  int j = jt * 32 + jl;

  __shared__ float buf[8224];   // kq [32][256] staging, then p [32 j][257]
  __shared__ float red[512];

  const float* ktb = kqall + 20 * KD * HW;
  float ktr[KD];
#pragma unroll
  for (int k = 0; k < KD; ++k) ktr[k] = ktb[((size_t)n * KD + k) * HW + j];
  const float* kqb = kqall + (size_t)(l * 4 + b) * KD * HW;
  for (int s = t; s < KD * HW; s += 256) buf[s] = kqb[s];
  __syncthreads();

  float v[32];
#pragma unroll
  for (int ii = 0; ii < 32; ++ii) v[ii] = 0.f;
  for (int k = 0; k < KD; ++k) {
    float a = ktr[k];
    const float4* q4 = (const float4*)&buf[k * 256 + iq * 32];
#pragma unroll
    for (int q = 0; q < 8; ++q) {
      float4 u = q4[q];
      v[q * 4 + 0] += u.x * a; v[q * 4 + 1] += u.y * a;
      v[q * 4 + 2] += u.z * a; v[q * 4 + 3] += u.w * a;
    }
  }
  float ml = -1e30f;
#pragma unroll
  for (int ii = 0; ii < 32; ++ii) ml = fmaxf(ml, v[ii]);
  float sl = 0.f;
#pragma unroll
  for (int ii = 0; ii < 32; ++ii) sl += __expf(v[ii] - ml);
  red[t] = ml;
  red[256 + t] = sl;
  __syncthreads();          // all buf(kq) reads done too
  float M = -1e30f;
#pragma unroll
  for (int q = 0; q < 8; ++q) M = fmaxf(M, red[q * 32 + jl]);
  float Ssum = 0.f;
#pragma unroll
  for (int q = 0; q < 8; ++q) Ssum += red[256 + q * 32 + jl] * __expf(red[q * 32 + jl] - M);
  float inv = 1.0f / Ssum;
  u16 tmp[32];
#pragma unroll
  for (int ii = 0; ii < 32; ++ii) {
    float pv = __expf(v[ii] - M) * inv;
    buf[jl * 257 + iq * 32 + ii] = pv;
    tmp[ii] = f2bf(pv);
  }
  // pT[(l*40+bn)*256 + j][i], thread writes its 32 contiguous bf16
  u16* prow = pT + (((size_t)(l * 40 + bn) * 256 + j) << 8) + iq * 32;
#pragma unroll
  for (int q = 0; q < 4; ++q) {
    uint4 w;
    w.x = (unsigned)tmp[q * 8 + 0] | ((unsigned)tmp[q * 8 + 1] << 16);
    w.y = (unsigned)tmp[q * 8 + 2] | ((unsigned)tmp[q * 8 + 3] << 16);
    w.z = (unsigned)tmp[q * 8 + 4] | ((unsigned)tmp[q * 8 + 5] << 16);
    w.w = (unsigned)tmp[q * 8 + 6] | ((unsigned)tmp[q * 8 + 7] << 16);
    reinterpret_cast<uint4*>(prow)[q] = w;
  }
  __syncthreads();

  // ---- aggn: [128 c][32 j] via MFMA; wave w owns c-tiles {2w, 2w+1} ----
  int w = t >> 6, lane = t & 63;
  int row = lane & 15, kg = lane >> 4;
  f4v acc[2][2] = {{{0.f,0.f,0.f,0.f},{0.f,0.f,0.f,0.f}},
                   {{0.f,0.f,0.f,0.f},{0.f,0.f,0.f,0.f}}};
  for (int kc = 0; kc < 8; ++kc) {
    bf8v ah[2], al[2];
#pragma unroll
    for (int ctl = 0; ctl < 2; ++ctl) {
      int ct = w * 2 + ctl;
      const u16* vh = vt2 + ((size_t)n * VD + ct * 16 + row) * 256 + kc * 32 + kg * 8;
      ah[ctl] = *reinterpret_cast<const bf8v*>(vh);
      al[ctl] = *reinterpret_cast<const bf8v*>(vh + 327680);
    }
#pragma unroll
    for (int jt2 = 0; jt2 < 2; ++jt2) {
      union { u16 u[8]; bf8v v8; } Bh;
#pragma unroll
      for (int e = 0; e < 8; ++e)
        Bh.u[e] = f2bf(buf[(jt2 * 16 + row) * 257 + kc * 32 + kg * 8 + e]);
#pragma unroll
      for (int ctl = 0; ctl < 2; ++ctl) {
        acc[ctl][jt2] = mfma16(ah[ctl], Bh.v8, acc[ctl][jt2]);
        acc[ctl][jt2] = mfma16(al[ctl], Bh.v8, acc[ctl][jt2]);
      }
    }
  }
  float* ab = aggn + (size_t)(l * 40 + bn) * VD * HW;
#pragma unroll
  for (int ctl = 0; ctl < 2; ++ctl)
#pragma unroll
    for (int jt2 = 0; jt2 < 2; ++jt2)
#pragma unroll
      for (int i = 0; i < 4; ++i)
        ab[(size_t)(w * 32 + ctl * 16 + kg * 4 + i) * HW + jt * 32 + jt2 * 16 + row]
            = acc[ctl][jt2][i];
}

// ---------------------------------------------------------------------------
// FA2: pure fa expansion from bf16 pT. block = (l, bn, jg of 16 j).
// Stage 16 rows (8 KB read) -> fp32 LDS -> bilinear -> nontemporal writes.
// grid = 3200 (level-major: 640 blocks per level, level 0 first).
__global__ __launch_bounds__(256) void k_fa2(
    const u16* __restrict__ pT, float* __restrict__ out) {
  int blk = blockIdx.x;
  int l = blk / 640;
  int local = blk % 640;
  int bn = local >> 4, jg = local & 15;
  int tid = threadIdx.x;
  __shared__ float ld[16][257];
  {
    int jj = tid >> 4, i0 = (tid & 15) * 16;
    const u16* src = pT + (((size_t)(l * 40 + bn) * 256 + jg * 16 + jj) << 8) + i0;
    const uint4* s4 = reinterpret_cast<const uint4*>(src);
    uint4 w0 = s4[0], w1 = s4[1];
    const unsigned* u0 = (const unsigned*)&w0;
    const unsigned* u1 = (const unsigned*)&w1;
#pragma unroll
    for (int e = 0; e < 4; ++e) {
      ld[jj][i0 + e * 2]     = bf2f((u16)(u0[e] & 0xffff));
      ld[jj][i0 + e * 2 + 1] = bf2f((u16)(u0[e] >> 16));
      ld[jj][i0 + 8 + e * 2]     = bf2f((u16)(u1[e] & 0xffff));
      ld[jj][i0 + 8 + e * 2 + 1] = bf2f((u16)(u1[e] >> 16));
    }
  }
  __syncthreads();

  int S_ = 64 >> l, shift = 6 - l, SS = S_ * S_;
  const size_t fa_off[5] = {5586944, 47529984, 58015744, 60637184, 61292544};
  float* ob = out + fa_off[l] + ((size_t)bn * HW + jg * 16) * SS;
  int tot = SS << 4;
  for (int base = tid * 4; base < tot; base += 1024) {
    int jj = base >> (2 * shift);
    int rest = base & (SS - 1);
    int X0 = rest & (S_ - 1), Y = rest >> shift;
    float cyf = (float)(Y * 15) / (float)(S_ - 1);
    int ylo = imin((int)cyf, 14); float fy = cyf - (float)ylo;
    const float* prow = &ld[jj][0];
    f4v rv;
#pragma unroll
    for (int t4 = 0; t4 < 4; ++t4) {
      int X = X0 + t4;
      float cxf = (float)(X * 15) / (float)(S_ - 1);
      int xlo = imin((int)cxf, 14); float fx = cxf - (float)xlo;
      int i00 = ylo * 16 + xlo;
      float v0 = prow[i00],      v1 = prow[i00 + 1];
      float v2 = prow[i00 + 16], v3 = prow[i00 + 17];
      rv[t4] = (1.f - fy) * ((1.f - fx) * v0 + fx * v1)
             + fy * ((1.f - fx) * v2 + fx * v3);
    }
    __builtin_nontemporal_store(rv, (f4v*)(ob + (size_t)jj * SS + rest));
  }
}

// ---------------------------------------------------------------------------
// Merged fuse+g16 (unchanged from r14). grid = 640.
__global__ __launch_bounds__(256) void k_g16f(
    const float* __restrict__ f16v, const float* __restrict__ aggn,
    const u16* __restrict__ cw2A, float* __restrict__ g16_all) {
  int blk = blockIdx.x;
  int ohalf = blk & 1;
  int img = blk >> 5, jc = (blk >> 1) & 15;
  int j0 = jc * 16;
  int l = img >> 2, b = img & 3;
  int tid = threadIdx.x;
  __shared__ __align__(16) u16 fsbh[16][280];   // [j][c], padded rows
  __shared__ __align__(16) u16 fsbl[16][280];
  int jj = tid & 15;
  int c0 = tid >> 4;
  for (int pass = 0; pass < 16; ++pass) {
    int cc = pass * 16 + c0;
    float v;
    if (cc < 128) {
      v = f16v[((size_t)img * VD + cc) * HW + j0 + jj];
    } else {
      const float* ab = aggn + ((size_t)(l * 40 + b * 10) * VD + cc - 128) * HW + j0 + jj;
      v = 0.f;
#pragma unroll
      for (int n = 0; n < NCLS; ++n) v += ab[(size_t)n * VD * HW];
    }
    u16 h = f2bf(v);
    fsbh[jj][cc] = h;
    fsbl[jj][cc] = f2bf(v - bf2f(h));
  }
  __syncthreads();

  int w = tid >> 6, lane = tid & 63;
  int row = lane & 15, kg = lane >> 4;
#pragma unroll
  for (int q = 0; q < 2; ++q) {
    int ot = ohalf * 8 + w * 2 + q;
    const u16* Ah = cw2A + (size_t)l * 65536 + ((size_t)(ot * 16 + row)) * 256 + kg * 8;
    const u16* Al = Ah + 327680;
    f4v acc = {0.f, 0.f, 0.f, 0.f};
#pragma unroll
    for (int kc = 0; kc < 8; ++kc) {
      bf8v ah = *reinterpret_cast<const bf8v*>(Ah + kc * 32);
      bf8v al = *reinterpret_cast<const bf8v*>(Al + kc * 32);
      bf8v bh = *reinterpret_cast<const bf8v*>(&fsbh[row][kc * 32 + kg * 8]);
      bf8v bl = *reinterpret_cast<const bf8v*>(&fsbl[row][kc * 32 + kg * 8]);
      acc = mfma16(ah, bh, acc);
      acc = mfma16(ah, bl, acc);
      acc = mfma16(al, bh, acc);
    }
#pragma unroll
    for (int i = 0; i < 4; ++i)
      g16_all[((size_t)img * CIN + ot * 16 + kg * 4 + i) * HW + j0 + row] = acc[i];
  }
}

// ---------------------------------------------------------------------------
// Final: out = cw[:, :256].f (MFMA) + bilinear(g16) + cb. grid = 5456.
__global__ __launch_bounds__(256) void k_out_final(
    const u16* __restrict__ cwA, const u16* __restrict__ Xf,
    const float* __restrict__ g16_all, const float* __restrict__ cb_all,
    float* __restrict__ out) {
  int wid = blockIdx.x * 4 + (threadIdx.x >> 6);
  int lane = threadIdx.x & 63;
  int pt = wid >> 4, octile = wid & 15;
  int l, lb, tl;
  if (pt < 1024)      { l = 0; lb = 0;    tl = 256; }
  else if (pt < 1280) { l = 1; lb = 1024; tl = 64; }
  else if (pt < 1344) { l = 2; lb = 1280; tl = 16; }
  else if (pt < 1360) { l = 3; lb = 1344; tl = 4; }
  else                { l = 4; lb = 1360; tl = 1; }
  int rem = pt - lb;
  int b = rem / tl;
  int pxin = (rem % tl) * 16;
  const size_t ooff[5] = {0, 4194304, 5242880, 5505024, 5570560};
  int S = 64 >> l, SS = S * S, shift = 6 - l;
  int row = lane & 15, kg = lane >> 4;
  int gpx = c_jbase[l] + b * SS + pxin + row;

  const u16* Ah = cwA + ((size_t)(octile * 16 + row)) * 256 + kg * 8;
  const u16* Al = Ah + 65536;
  const u16* Bh = Xf + (size_t)gpx * 512 + kg * 8;
  const u16* Bl = Bh + 256;
  f4v acc = {0.f, 0.f, 0.f, 0.f};
#pragma unroll
  for (int kc = 0; kc < 8; ++kc) {
    bf8v ah = *reinterpret_cast<const bf8v*>(Ah + kc * 32);
    bf8v al = *reinterpret_cast<const bf8v*>(Al + kc * 32);
    bf8v bh = *reinterpret_cast<const bf8v*>(Bh + kc * 32);
    bf8v bl = *reinterpret_cast<const bf8v*>(Bl + kc * 32);
    acc = mfma16(ah, bh, acc);
    acc = mfma16(ah, bl, acc);
    acc = mfma16(al, bh, acc);
  }

  int px = pxin + row;
  int Xc = px & (S - 1), Y = px >> shift;
  float cyf = (float)(Y * 15) / (float)(S - 1);
  int ylo = imin((int)cyf, 14); float fy = cyf - (float)ylo;
  float cxf = (float)(Xc * 15) / (float)(S - 1);
  int xlo = imin((int)cxf, 14); float fx = cxf - (float)xlo;
  int i00 = ylo * 16 + xlo;
  const float* gbase = g16_all + ((size_t)(l * 4 + b) * CIN + octile * 16 + kg * 4) * HW;
  float* ob = out + ooff[l] + ((size_t)b * CIN + octile * 16) * SS + px;
#pragma unroll
  for (int i = 0; i < 4; ++i) {
    const float* g = gbase + (size_t)i * HW + i00;
    float v0 = g[0], v1 = g[1], v2 = g[16], v3 = g[17];
    float bil = (1.f - fy) * ((1.f - fx) * v0 + fx * v1)
              + fy * ((1.f - fx) * v2 + fx * v3);
    float r = acc[i] + bil + cb_all[l * CIN + octile * 16 + kg * 4 + i];
    __builtin_nontemporal_store(r, ob + (size_t)(kg * 4 + i) * SS);
  }
}

// ===========================================================================
extern "C" void kernel_launch(void* const* d_in, const int* in_sizes, int n_in,
                              void* d_out, int out_size, void* d_ws, size_t ws_size,
                              hipStream_t stream) {
  const float* feat[5];
  for (int l = 0; l < 5; ++l) feat[l] = (const float*)d_in[l];
  const float* att   = (const float*)d_in[5];
  const float* ktw   = (const float*)d_in[6];
  const float* ktb   = (const float*)d_in[7];
  const float* vtw   = (const float*)d_in[8];
  const float* vtb   = (const float*)d_in[9];
  const float* kqw   = (const float*)d_in[10];
  const float* kqb   = (const float*)d_in[11];
  const float* vqw   = (const float*)d_in[12];
  const float* vqb   = (const float*)d_in[13];
  const float* gamma = (const float*)d_in[14];
  const float* beta  = (const float*)d_in[15];
  const float* cw    = (const float*)d_in[16];
  const float* cbias = (const float*)d_in[17];
  float* out = (float*)d_out;

  // workspace layout (floats)
  float* ws    = (float*)d_ws;
  float* kqall = ws;                     // [30][32][256]        245760
  float* f16v  = ws + 245760;            // [20][128][256]       655360 (vq*10)
  u16*   vt2   = (u16*)(ws + 901120);    // [2][10][128][256]u16 327680 fl
  u16*   cwA   = (u16*)(ws + 1228800);   // [2][256][256] u16    65536 fl
  u16*   cw2A  = (u16*)(ws + 1294336);   // [2][5][256][256]u16  327680 fl
  float* cb    = ws + 1622016;           // [5][256]             1280
  u16*   Xf    = (u16*)(ws + 1623296);   // [21824][512] u16     5586944 fl
  float* S0    = ws + 7210240;           // shared region
  // conv phase:
  u16*   Awv  = (u16*)S0;                  // 3538944 u16 = 1769472 fl
  u16*   Awk  = (u16*)(S0 + 1769472);      //  884736 u16 = 442368 fl
  u16*   Xr   = (u16*)(S0 + 2211840);      // [30][256][512] u16 = 1966080 fl
  u16*   zrow = (u16*)(S0 + 4177920);      // 512 u16 = 256 fl
  // post phases:
  float* aggn    = S0;                     // [200][128][256] = 6553600 fl
  float* g16_all = S0 + 6553600;           // [20][256][256] = 1310720 fl
  u16*   pT      = (u16*)(S0 + 7864320);   // [200][256][256] u16 = 6553600 fl

  // Phase 1: merged preps, then resize + conv
  k_prep1<<<1853, 256, 0, stream>>>(
      feat[0], feat[1], feat[2], feat[3], feat[4], att,
      vqw, vtw, kqw, ktw, cw, gamma, cbias, beta,
      Xf, Xr, Awv, Awk, cwA, cw2A, cb);
  k_prep_xr<<<320, 256, 0, stream>>>(Xf, Xr, zrow);
  k_conv_mfma<<<600, 256, 0, stream>>>(
      Xr, Awv, Awk, zrow, kqall, vt2, f16v, vqb, vtb, kqb, ktb);

  // Phase 2: p + aggn (compute), then pure fa expansion (streaming writes)
  k_pagg<<<1600, 256, 0, stream>>>(kqall, vt2, pT, aggn);
  k_fa2<<<3200, 256, 0, stream>>>(pT, out);

  // Phase 3: combine
  k_g16f<<<640, 256, 0, stream>>>(f16v, aggn, cw2A, g16_all);
  k_out_final<<<5456, 256, 0, stream>>>(cwA, Xf, g16_all, cb, out);
}

// Round 16
// 327.622 us; speedup vs baseline: 1.0918x; 1.0918x over previous
//
#include <hip/hip_runtime.h>

// Problem constants
constexpr int CIN   = 256;   // feature channels
constexpr int KD    = 32;    // key dim
constexpr int VD    = 128;   // value dim
constexpr int NCLS  = 10;
constexpr int BS    = 4;
constexpr int HW    = 256;   // 16*16
constexpr float BNC = 0.9999950000374997f; // 1/sqrt(1+1e-5)

typedef unsigned short u16;
typedef __attribute__((ext_vector_type(8))) __bf16 bf8v;
typedef __attribute__((ext_vector_type(4))) float f4v;

static __device__ __forceinline__ int imin(int a, int b) { return a < b ? a : b; }

static __device__ __forceinline__ u16 f2bf(float v) {
  union { float f; unsigned u; } x; x.f = v;
  unsigned r = x.u + 0x7FFFu + ((x.u >> 16) & 1u);
  return (u16)(r >> 16);
}
static __device__ __forceinline__ float bf2f(u16 h) {
  union { unsigned u; float f; } x; x.u = ((unsigned)h) << 16;
  return x.f;
}

static __device__ __forceinline__ f4v mfma16(bf8v a, bf8v b, f4v c) {
  return __builtin_amdgcn_mfma_f32_16x16x32_bf16(a, b, c, 0, 0, 0);
}

__constant__ const int c_jbase[5] = {0, 16384, 20480, 21504, 21760};

// ---------------------------------------------------------------------------
// Merged independent preps (unchanged).
__global__ __launch_bounds__(256) void k_prep1(
    const float* __restrict__ f0, const float* __restrict__ f1,
    const float* __restrict__ f2, const float* __restrict__ f3,
    const float* __restrict__ f4, const float* __restrict__ att,
    const float* __restrict__ vqw, const float* __restrict__ vtw,
    const float* __restrict__ kqw, const float* __restrict__ ktw,
    const float* __restrict__ cw, const float* __restrict__ gamma,
    const float* __restrict__ cbias, const float* __restrict__ beta,
    u16* __restrict__ Xf, u16* __restrict__ Xr,
    u16* __restrict__ Awv, u16* __restrict__ Awk,
    u16* __restrict__ cwA, u16* __restrict__ cw2A, float* __restrict__ cb) {
  __shared__ float sm[16][65];
  int blk = blockIdx.x;
  int tid = threadIdx.x;
  if (blk < 384) {
    const float* fin; u16* dstbase; int SS, px0;
    if (blk < 344) {
      int l, base, nb;
      if (blk < 256)      { l = 0; base = 0;   nb = 64; }
      else if (blk < 320) { l = 1; base = 256; nb = 16; }
      else if (blk < 336) { l = 2; base = 320; nb = 4; }
      else if (blk < 340) { l = 3; base = 336; nb = 1; }
      else                { l = 4; base = 340; nb = 1; }
      int local = blk - base;
      int b = local / nb, chunk = local % nb;
      int S = 64 >> l; SS = S * S;
      px0 = chunk * 64;
      fin = (l == 0 ? f0 : l == 1 ? f1 : l == 2 ? f2 : l == 3 ? f3 : f4)
            + (size_t)b * CIN * SS;
      dstbase = Xf + (size_t)(c_jbase[l] + b * SS) * 512;
    } else {
      int a = blk - 344;
      int imgA = a >> 2, chunk = a & 3;
      SS = 256; px0 = chunk * 64;
      fin = att + (size_t)imgA * CIN * 256;
      dstbase = Xr + (size_t)(20 + imgA) * 131072;
    }
    int px_r = tid & 63, cr = tid >> 6;
    int px_w = tid >> 2, c4 = (tid & 3) * 4;
    for (int cbk = 0; cbk < 16; ++cbk) {
      __syncthreads();
#pragma unroll
      for (int q = 0; q < 4; ++q) {
        int cl = q * 4 + cr;
        float v = 0.f;
        if (px0 + px_r < SS) v = fin[(size_t)(cbk * 16 + cl) * SS + px0 + px_r];
        sm[cl][px_r] = v;
      }
      __syncthreads();
      if (px0 + px_w < SS) {
        u16 hh[4], ll[4];
#pragma unroll
        for (int e = 0; e < 4; ++e) {
          float v = sm[c4 + e][px_w];
          hh[e] = f2bf(v); ll[e] = f2bf(v - bf2f(hh[e]));
        }
        uint2 wh, wl;
        wh.x = (unsigned)hh[0] | ((unsigned)hh[1] << 16); wh.y = (unsigned)hh[2] | ((unsigned)hh[3] << 16);
        wl.x = (unsigned)ll[0] | ((unsigned)ll[1] << 16); wl.y = (unsigned)ll[2] | ((unsigned)ll[3] << 16);
        u16* dst = dstbase + (size_t)(px0 + px_w) * 512 + cbk * 16 + c4;
        *reinterpret_cast<uint2*>(dst) = wh;
        *reinterpret_cast<uint2*>(dst + 256) = wl;
      }
    }
  } else if (blk < 1464) {
    int gid = (blk - 384) * 256 + tid;
    int lane = gid & 63;
    int grp = gid >> 6;
    const float* src; u16* dst; int kc;
    if (grp < 3456) {
      kc = grp % 72; int ot = (grp / 72) % 8; int sid = grp / (72 * 8);
      src = (sid < 5 ? vqw + (size_t)sid * VD * 2304 : vtw) + (size_t)(ot * 16 + (lane & 15)) * 2304;
      dst = Awv + (size_t)grp * 1024;
    } else {
      int g2 = grp - 3456;
      kc = g2 % 72; int ot = (g2 / 72) % 2; int sid = g2 / 144;
      src = (sid < 5 ? kqw + (size_t)sid * KD * 2304 : ktw) + (size_t)(ot * 16 + (lane & 15)) * 2304;
      dst = Awk + (size_t)g2 * 1024;
    }
    int q0 = (lane >> 4) * 8;
    int t = kc >> 3, c0 = (kc & 7) * 32;
#pragma unroll
    for (int i = 0; i < 8; ++i) {
      int c = c0 + q0 + i;
      float v = src[c * 9 + t];
      u16 h = f2bf(v);
      dst[lane * 8 + i] = h;
      dst[512 + lane * 8 + i] = f2bf(v - bf2f(h));
    }
  } else if (blk < 1848) {
    int blk2 = blk - 1464;
    if (blk2 < 64) {
      int gid = blk2 * 256 + tid;
      int oc = gid >> 6, c0 = (gid & 63) * 4;
      float4 v = *reinterpret_cast<const float4*>(cw + (size_t)oc * 512 + c0);
      const float* vv = (const float*)&v;
      u16 h[4], l[4];
#pragma unroll
      for (int e = 0; e < 4; ++e) { h[e] = f2bf(vv[e]); l[e] = f2bf(vv[e] - bf2f(h[e])); }
      uint2 wh, wl;
      wh.x = (unsigned)h[0] | ((unsigned)h[1] << 16); wh.y = (unsigned)h[2] | ((unsigned)h[3] << 16);
      wl.x = (unsigned)l[0] | ((unsigned)l[1] << 16); wl.y = (unsigned)l[2] | ((unsigned)l[3] << 16);
      *reinterpret_cast<uint2*>(cwA + (size_t)oc * 256 + c0) = wh;
      *reinterpret_cast<uint2*>(cwA + 65536 + (size_t)oc * 256 + c0) = wl;
    } else {
      int gid = (blk2 - 64) * 256 + tid;
      int l = gid / 16384, rem = gid % 16384;
      int oc = rem >> 6, c0 = (rem & 63) * 4;
      u16 h[4], lo[4];
#pragma unroll
      for (int e = 0; e < 4; ++e) {
        int c = c0 + e;
        float v = cw[(size_t)oc * 512 + 256 + c] * (gamma[l * 256 + c] * BNC);
        h[e] = f2bf(v); lo[e] = f2bf(v - bf2f(h[e]));
      }
      uint2 wh, wl;
      wh.x = (unsigned)h[0] | ((unsigned)h[1] << 16); wh.y = (unsigned)h[2] | ((unsigned)h[3] << 16);
      wl.x = (unsigned)lo[0] | ((unsigned)lo[1] << 16); wl.y = (unsigned)lo[2] | ((unsigned)lo[3] << 16);
      *reinterpret_cast<uint2*>(cw2A + (size_t)l * 65536 + oc * 256 + c0) = wh;
      *reinterpret_cast<uint2*>(cw2A + 327680 + (size_t)l * 65536 + oc * 256 + c0) = wl;
    }
  } else {
    int l = blk - 1848, oc = tid;
    float s = cbias[oc];
    for (int c = 0; c < CIN; ++c)
      s += cw[(size_t)oc * 512 + 256 + c] * beta[l * CIN + c];
    cb[l * CIN + oc] = s;
  }
}

// ---------------------------------------------------------------------------
// Level imgs: bilinear-resize Xf rows -> Xr[img][px][2][256]. grid = 320.
__global__ __launch_bounds__(256) void k_prep_xr(
    const u16* __restrict__ Xf, u16* __restrict__ Xr, u16* __restrict__ zrow) {
  int blk = blockIdx.x;
  int img = blk >> 4, yr = blk & 15;
  int l = img >> 2, b = img & 3;
  int S = 64 >> l, SS = S * S;
  int c = threadIdx.x;
  if (blk == 0) { zrow[c] = 0; zrow[256 + c] = 0; }
  float cyf = (float)(yr * (S - 1)) / 15.0f;
  int ylo = imin((int)cyf, S - 2); float fy = cyf - (float)ylo;
  u16* dst = Xr + ((size_t)img * 256 + yr * 16) * 512;
  const u16* srcb = Xf + (size_t)(c_jbase[l] + b * SS) * 512;
  for (int x = 0; x < 16; ++x) {
    float cxf = (float)(x * (S - 1)) / 15.0f;
    int xlo = imin((int)cxf, S - 2); float fx = cxf - (float)xlo;
    const u16* r00 = srcb + (size_t)(ylo * S + xlo) * 512;
    const u16* r10 = srcb + (size_t)((ylo + 1) * S + xlo) * 512;
    float v00 = bf2f(r00[c]) + bf2f(r00[256 + c]);
    float v01 = bf2f(r00[512 + c]) + bf2f(r00[768 + c]);
    float v10 = bf2f(r10[c]) + bf2f(r10[256 + c]);
    float v11 = bf2f(r10[512 + c]) + bf2f(r10[768 + c]);
    float v = (1.f - fy) * ((1.f - fx) * v00 + fx * v01)
            + fy * ((1.f - fx) * v10 + fx * v11);
    u16 h = f2bf(v);
    dst[x * 512 + c] = h;
    dst[x * 512 + 256 + c] = f2bf(v - bf2f(h));
  }
}

// ---------------------------------------------------------------------------
// MFMA conv from Xr (unchanged).
__global__ __launch_bounds__(256) void k_conv_mfma(
    const u16* __restrict__ Xr, const u16* __restrict__ Awv, const u16* __restrict__ Awk,
    const u16* __restrict__ zrow,
    float* __restrict__ kqall, u16* __restrict__ vt2, float* __restrict__ f16v,
    const float* __restrict__ vqb, const float* __restrict__ vtb,
    const float* __restrict__ kqb, const float* __restrict__ ktb) {
  int wid = blockIdx.x * 4 + (threadIdx.x >> 6);
  int lane = threadIdx.x & 63;
  bool isV = wid < 1920;
  int img, ot, yp;
  if (isV) { img = wid >> 6; int r = wid & 63; ot = r >> 3; yp = r & 7; }
  else     { int j = wid - 1920; img = j >> 4; int r = j & 15; ot = r >> 3; yp = r & 7; }
  int wset = img < 20 ? (img >> 2) : 5;

  const u16* Ab = isV ? Awv + ((size_t)(wset * 8 + ot)) * 72 * 1024
                      : Awk + ((size_t)(wset * 2 + ot)) * 72 * 1024;
  const u16* Xb = Xr + (size_t)img * 131072;
  int xcol = lane & 15, kg = lane >> 4;
  int y0 = yp * 2, y1 = y0 + 1;

  f4v acc0 = {0.f, 0.f, 0.f, 0.f}, acc1 = {0.f, 0.f, 0.f, 0.f};
  for (int t = 0; t < 9; ++t) {
    int dy = (t >= 6) ? 2 : (t >= 3 ? 1 : 0);
    int dx = t - dy * 3;
    int yy0 = y0 + dy - 1, yy1 = yy0 + 1;
    int xx = xcol + dx - 1;
    bool xok = (unsigned)xx < 16u;
    const u16* base0 = (xok && (unsigned)yy0 < 16u)
                       ? Xb + (size_t)(yy0 * 16 + xx) * 512 : zrow;
    const u16* base1 = (xok && (unsigned)yy1 < 16u)
                       ? Xb + (size_t)(yy1 * 16 + xx) * 512 : zrow;
    const u16* Xr0 = base0 + kg * 8;
    const u16* Xr1 = base1 + kg * 8;
    const u16* Ak = Ab + (size_t)t * 8 * 1024 + lane * 8;
#pragma unroll
    for (int cc = 0; cc < 8; ++cc) {
      bf8v ah = *reinterpret_cast<const bf8v*>(Ak + cc * 1024);
      bf8v al = *reinterpret_cast<const bf8v*>(Ak + cc * 1024 + 512);
      bf8v bh0 = *reinterpret_cast<const bf8v*>(Xr0 + cc * 32);
      bf8v bl0 = *reinterpret_cast<const bf8v*>(Xr0 + cc * 32 + 256);
      bf8v bh1 = *reinterpret_cast<const bf8v*>(Xr1 + cc * 32);
      bf8v bl1 = *reinterpret_cast<const bf8v*>(Xr1 + cc * 32 + 256);
      acc0 = mfma16(ah, bh0, acc0);
      acc0 = mfma16(ah, bl0, acc0);
      acc0 = mfma16(al, bh0, acc0);
      acc1 = mfma16(ah, bh1, acc1);
      acc1 = mfma16(ah, bl1, acc1);
      acc1 = mfma16(al, bh1, acc1);
    }
  }

  int ocbase = ot * 16;
  if (isV && img >= 20) {
    int n = img - 20;
    u16* d2 = vt2 + ((size_t)n * VD + ocbase) * HW;
#pragma unroll
    for (int i = 0; i < 4; ++i) {
      int ocl = kg * 4 + i;
      float bv = vtb[ocbase + ocl];
      float va = acc0[i] + bv, vb = acc1[i] + bv;
      u16 ha = f2bf(va), hb = f2bf(vb);
      size_t ia = (size_t)ocl * HW + y0 * 16 + xcol;
      size_t ib = (size_t)ocl * HW + y1 * 16 + xcol;
      d2[ia] = ha; d2[ia + 327680] = f2bf(va - bf2f(ha));
      d2[ib] = hb; d2[ib + 327680] = f2bf(vb - bf2f(hb));
    }
    return;
  }
  float scale = 1.f;
  const float* bias;
  float* dst;
  if (isV) { dst = f16v + ((size_t)img * VD + ocbase) * HW; bias = vqb + wset * VD + ocbase; scale = (float)NCLS; }
  else if (img < 20) { dst = kqall + ((size_t)img * KD + ocbase) * HW; bias = kqb + wset * KD + ocbase; }
  else { dst = kqall + (size_t)20 * KD * HW + ((size_t)(img - 20) * KD + ocbase) * HW; bias = ktb + ocbase; }
#pragma unroll
  for (int i = 0; i < 4; ++i) {
    int ocl = kg * 4 + i;
    float bv = bias[ocl];
    dst[(size_t)ocl * HW + y0 * 16 + xcol] = (acc0[i] + bv) * scale;
    dst[(size_t)ocl * HW + y1 * 16 + xcol] = (acc1[i] + bv) * scale;
  }
}

// ---------------------------------------------------------------------------
// PAGG: block = (l, bn, jt of 32 j): QK^T -> softmax -> p (LDS fp32 + pT bf16)
// -> aggn MFMA. grid = 1600 x 256. (unchanged from r15)
__global__ __launch_bounds__(256) void k_pagg(
    const float* __restrict__ kqall, const u16* __restrict__ vt2,
    u16* __restrict__ pT, float* __restrict__ aggn) {
  int blk = blockIdx.x;
  int l = blk / 320;
  int g = blk % 320;
  int bn = g >> 3, jt = g & 7;
  int b = bn / NCLS, n = bn % NCLS;
  int t = threadIdx.x;
  int iq = t >> 5, jl = t & 31;
  int j = jt * 32 + jl;

  __shared__ float buf[8224];   // kq [32][256] staging, then p [32 j][257]
  __shared__ float red[512];

  const float* ktb = kqall + 20 * KD * HW;
  float ktr[KD];
#pragma unroll
  for (int k = 0; k < KD; ++k) ktr[k] = ktb[((size_t)n * KD + k) * HW + j];
  const float* kqb = kqall + (size_t)(l * 4 + b) * KD * HW;
  for (int s = t; s < KD * HW; s += 256) buf[s] = kqb[s];
  __syncthreads();

  float v[32];
#pragma unroll
  for (int ii = 0; ii < 32; ++ii) v[ii] = 0.f;
  for (int k = 0; k < KD; ++k) {
    float a = ktr[k];
    const float4* q4 = (const float4*)&buf[k * 256 + iq * 32];
#pragma unroll
    for (int q = 0; q < 8; ++q) {
      float4 u = q4[q];
      v[q * 4 + 0] += u.x * a; v[q * 4 + 1] += u.y * a;
      v[q * 4 + 2] += u.z * a; v[q * 4 + 3] += u.w * a;
    }
  }
  float ml = -1e30f;
#pragma unroll
  for (int ii = 0; ii < 32; ++ii) ml = fmaxf(ml, v[ii]);
  float sl = 0.f;
#pragma unroll
  for (int ii = 0; ii < 32; ++ii) sl += __expf(v[ii] - ml);
  red[t] = ml;
  red[256 + t] = sl;
  __syncthreads();          // all buf(kq) reads done too
  float M = -1e30f;
#pragma unroll
  for (int q = 0; q < 8; ++q) M = fmaxf(M, red[q * 32 + jl]);
  float Ssum = 0.f;
#pragma unroll
  for (int q = 0; q < 8; ++q) Ssum += red[256 + q * 32 + jl] * __expf(red[q * 32 + jl] - M);
  float inv = 1.0f / Ssum;
  u16 tmp[32];
#pragma unroll
  for (int ii = 0; ii < 32; ++ii) {
    float pv = __expf(v[ii] - M) * inv;
    buf[jl * 257 + iq * 32 + ii] = pv;
    tmp[ii] = f2bf(pv);
  }
  u16* prow = pT + (((size_t)(l * 40 + bn) * 256 + j) << 8) + iq * 32;
#pragma unroll
  for (int q = 0; q < 4; ++q) {
    uint4 w;
    w.x = (unsigned)tmp[q * 8 + 0] | ((unsigned)tmp[q * 8 + 1] << 16);
    w.y = (unsigned)tmp[q * 8 + 2] | ((unsigned)tmp[q * 8 + 3] << 16);
    w.z = (unsigned)tmp[q * 8 + 4] | ((unsigned)tmp[q * 8 + 5] << 16);
    w.w = (unsigned)tmp[q * 8 + 6] | ((unsigned)tmp[q * 8 + 7] << 16);
    reinterpret_cast<uint4*>(prow)[q] = w;
  }
  __syncthreads();

  int w = t >> 6, lane = t & 63;
  int row = lane & 15, kg = lane >> 4;
  f4v acc[2][2] = {{{0.f,0.f,0.f,0.f},{0.f,0.f,0.f,0.f}},
                   {{0.f,0.f,0.f,0.f},{0.f,0.f,0.f,0.f}}};
  for (int kc = 0; kc < 8; ++kc) {
    bf8v ah[2], al[2];
#pragma unroll
    for (int ctl = 0; ctl < 2; ++ctl) {
      int ct = w * 2 + ctl;
      const u16* vh = vt2 + ((size_t)n * VD + ct * 16 + row) * 256 + kc * 32 + kg * 8;
      ah[ctl] = *reinterpret_cast<const bf8v*>(vh);
      al[ctl] = *reinterpret_cast<const bf8v*>(vh + 327680);
    }
#pragma unroll
    for (int jt2 = 0; jt2 < 2; ++jt2) {
      union { u16 u[8]; bf8v v8; } Bh;
#pragma unroll
      for (int e = 0; e < 8; ++e)
        Bh.u[e] = f2bf(buf[(jt2 * 16 + row) * 257 + kc * 32 + kg * 8 + e]);
#pragma unroll
      for (int ctl = 0; ctl < 2; ++ctl) {
        acc[ctl][jt2] = mfma16(ah[ctl], Bh.v8, acc[ctl][jt2]);
        acc[ctl][jt2] = mfma16(al[ctl], Bh.v8, acc[ctl][jt2]);
      }
    }
  }
  float* ab = aggn + (size_t)(l * 40 + bn) * VD * HW;
#pragma unroll
  for (int ctl = 0; ctl < 2; ++ctl)
#pragma unroll
    for (int jt2 = 0; jt2 < 2; ++jt2)
#pragma unroll
      for (int i = 0; i < 4; ++i)
        ab[(size_t)(w * 32 + ctl * 16 + kg * 4 + i) * HW + jt * 32 + jt2 * 16 + row]
            = acc[ctl][jt2][i];
}

// ---------------------------------------------------------------------------
// Merged fuse+g16 (unchanged). grid = 640.
__global__ __launch_bounds__(256) void k_g16f(
    const float* __restrict__ f16v, const float* __restrict__ aggn,
    const u16* __restrict__ cw2A, float* __restrict__ g16_all) {
  int blk = blockIdx.x;
  int ohalf = blk & 1;
  int img = blk >> 5, jc = (blk >> 1) & 15;
  int j0 = jc * 16;
  int l = img >> 2, b = img & 3;
  int tid = threadIdx.x;
  __shared__ __align__(16) u16 fsbh[16][280];   // [j][c], padded rows
  __shared__ __align__(16) u16 fsbl[16][280];
  int jj = tid & 15;
  int c0 = tid >> 4;
  for (int pass = 0; pass < 16; ++pass) {
    int cc = pass * 16 + c0;
    float v;
    if (cc < 128) {
      v = f16v[((size_t)img * VD + cc) * HW + j0 + jj];
    } else {
      const float* ab = aggn + ((size_t)(l * 40 + b * 10) * VD + cc - 128) * HW + j0 + jj;
      v = 0.f;
#pragma unroll
      for (int n = 0; n < NCLS; ++n) v += ab[(size_t)n * VD * HW];
    }
    u16 h = f2bf(v);
    fsbh[jj][cc] = h;
    fsbl[jj][cc] = f2bf(v - bf2f(h));
  }
  __syncthreads();

  int w = tid >> 6, lane = tid & 63;
  int row = lane & 15, kg = lane >> 4;
#pragma unroll
  for (int q = 0; q < 2; ++q) {
    int ot = ohalf * 8 + w * 2 + q;
    const u16* Ah = cw2A + (size_t)l * 65536 + ((size_t)(ot * 16 + row)) * 256 + kg * 8;
    const u16* Al = Ah + 327680;
    f4v acc = {0.f, 0.f, 0.f, 0.f};
#pragma unroll
    for (int kc = 0; kc < 8; ++kc) {
      bf8v ah = *reinterpret_cast<const bf8v*>(Ah + kc * 32);
      bf8v al = *reinterpret_cast<const bf8v*>(Al + kc * 32);
      bf8v bh = *reinterpret_cast<const bf8v*>(&fsbh[row][kc * 32 + kg * 8]);
      bf8v bl = *reinterpret_cast<const bf8v*>(&fsbl[row][kc * 32 + kg * 8]);
      acc = mfma16(ah, bh, acc);
      acc = mfma16(ah, bl, acc);
      acc = mfma16(al, bh, acc);
    }
#pragma unroll
    for (int i = 0; i < 4; ++i)
      g16_all[((size_t)img * CIN + ot * 16 + kg * 4 + i) * HW + j0 + row] = acc[i];
  }
}

// ---------------------------------------------------------------------------
// COMBO: fused out_final (5456 units, MFMA-bound) + fa expansion (3200 units,
// write-bound), interleaved 2:1 so compute and write pipes overlap.
// grid = 8656: blk<8184: g=blk/3, r=blk%3; r<2 -> OUT unit g*2+r, r==2 -> FA
// unit g. blk>=8184 -> FA unit 2728+(blk-8184).
__global__ __launch_bounds__(256) void k_combo(
    const u16* __restrict__ pT, const u16* __restrict__ cwA,
    const u16* __restrict__ Xf, const float* __restrict__ g16_all,
    const float* __restrict__ cb_all, float* __restrict__ out) {
  const size_t fa_off[5] = {5586944, 47529984, 58015744, 60637184, 61292544};
  const size_t ooff[5] = {0, 4194304, 5242880, 5505024, 5570560};
  __shared__ float ldp[16][257];

  int blk = blockIdx.x;
  int kind, unit;
  if (blk < 8184) {
    int g = blk / 3, r = blk - g * 3;
    if (r < 2) { kind = 0; unit = g * 2 + r; }
    else       { kind = 1; unit = g; }
  } else { kind = 1; unit = 2728 + (blk - 8184); }
  int tid = threadIdx.x;

  if (kind == 0) {
    // ---- out_final unit: 4 waves, each one (pt, octile) tile ----
    int wid = unit * 4 + (tid >> 6);
    int lane = tid & 63;
    int pt = wid >> 4, octile = wid & 15;
    int l, lb, tl;
    if (pt < 1024)      { l = 0; lb = 0;    tl = 256; }
    else if (pt < 1280) { l = 1; lb = 1024; tl = 64; }
    else if (pt < 1344) { l = 2; lb = 1280; tl = 16; }
    else if (pt < 1360) { l = 3; lb = 1344; tl = 4; }
    else                { l = 4; lb = 1360; tl = 1; }
    int rem = pt - lb;
    int b = rem / tl;
    int pxin = (rem % tl) * 16;
    int S = 64 >> l, SS = S * S, shift = 6 - l;
    int row = lane & 15, kg = lane >> 4;
    int gpx = c_jbase[l] + b * SS + pxin + row;

    const u16* Ah = cwA + ((size_t)(octile * 16 + row)) * 256 + kg * 8;
    const u16* Al = Ah + 65536;
    const u16* Bh = Xf + (size_t)gpx * 512 + kg * 8;
    const u16* Bl = Bh + 256;
    f4v acc = {0.f, 0.f, 0.f, 0.f};
#pragma unroll
    for (int kc = 0; kc < 8; ++kc) {
      bf8v ah = *reinterpret_cast<const bf8v*>(Ah + kc * 32);
      bf8v al = *reinterpret_cast<const bf8v*>(Al + kc * 32);
      bf8v bh = *reinterpret_cast<const bf8v*>(Bh + kc * 32);
      bf8v bl = *reinterpret_cast<const bf8v*>(Bl + kc * 32);
      acc = mfma16(ah, bh, acc);
      acc = mfma16(ah, bl, acc);
      acc = mfma16(al, bh, acc);
    }

    int px = pxin + row;
    int Xc = px & (S - 1), Y = px >> shift;
    float cyf = (float)(Y * 15) / (float)(S - 1);
    int ylo = imin((int)cyf, 14); float fy = cyf - (float)ylo;
    float cxf = (float)(Xc * 15) / (float)(S - 1);
    int xlo = imin((int)cxf, 14); float fx = cxf - (float)xlo;
    int i00 = ylo * 16 + xlo;
    const float* gbase = g16_all + ((size_t)(l * 4 + b) * CIN + octile * 16 + kg * 4) * HW;
    float* ob = out + ooff[l] + ((size_t)b * CIN + octile * 16) * SS + px;
#pragma unroll
    for (int i = 0; i < 4; ++i) {
      const float* g = gbase + (size_t)i * HW + i00;
      float v0 = g[0], v1 = g[1], v2 = g[16], v3 = g[17];
      float bil = (1.f - fy) * ((1.f - fx) * v0 + fx * v1)
                + fy * ((1.f - fx) * v2 + fx * v3);
      float r = acc[i] + bil + cb_all[l * CIN + octile * 16 + kg * 4 + i];
      __builtin_nontemporal_store(r, ob + (size_t)(kg * 4 + i) * SS);
    }
  } else {
    // ---- fa unit: stage 16 bf16 p-rows -> fp32 LDS -> bilinear -> out ----
    int l = unit / 640;
    int local = unit % 640;
    int bn = local >> 4, jg = local & 15;
    {
      int jj = tid >> 4, i0 = (tid & 15) * 16;
      const u16* src = pT + (((size_t)(l * 40 + bn) * 256 + jg * 16 + jj) << 8) + i0;
      const uint4* s4 = reinterpret_cast<const uint4*>(src);
      uint4 w0 = s4[0], w1 = s4[1];
      const unsigned* u0 = (const unsigned*)&w0;
      const unsigned* u1 = (const unsigned*)&w1;
#pragma unroll
      for (int e = 0; e < 4; ++e) {
        ldp[jj][i0 + e * 2]     = bf2f((u16)(u0[e] & 0xffff));
        ldp[jj][i0 + e * 2 + 1] = bf2f((u16)(u0[e] >> 16));
        ldp[jj][i0 + 8 + e * 2]     = bf2f((u16)(u1[e] & 0xffff));
        ldp[jj][i0 + 8 + e * 2 + 1] = bf2f((u16)(u1[e] >> 16));
      }
    }
    __syncthreads();

    int S_ = 64 >> l, shift = 6 - l, SS = S_ * S_;
    float* ob = out + fa_off[l] + ((size_t)bn * HW + jg * 16) * SS;
    int tot = SS << 4;
    for (int base = tid * 4; base < tot; base += 1024) {
      int jj = base >> (2 * shift);
      int rest = base & (SS - 1);
      int X0 = rest & (S_ - 1), Y = rest >> shift;
      float cyf = (float)(Y * 15) / (float)(S_ - 1);
      int ylo = imin((int)cyf, 14); float fy = cyf - (float)ylo;
      const float* prow = &ldp[jj][0];
      f4v rv;
#pragma unroll
      for (int t4 = 0; t4 < 4; ++t4) {
        int X = X0 + t4;
        float cxf = (float)(X * 15) / (float)(S_ - 1);
        int xlo = imin((int)cxf, 14); float fx = cxf - (float)xlo;
        int i00 = ylo * 16 + xlo;
        float v0 = prow[i00],      v1 = prow[i00 + 1];
        float v2 = prow[i00 + 16], v3 = prow[i00 + 17];
        rv[t4] = (1.f - fy) * ((1.f - fx) * v0 + fx * v1)
               + fy * ((1.f - fx) * v2 + fx * v3);
      }
      __builtin_nontemporal_store(rv, (f4v*)(ob + (size_t)jj * SS + rest));
    }
  }
}

// ===========================================================================
extern "C" void kernel_launch(void* const* d_in, const int* in_sizes, int n_in,
                              void* d_out, int out_size, void* d_ws, size_t ws_size,
                              hipStream_t stream) {
  const float* feat[5];
  for (int l = 0; l < 5; ++l) feat[l] = (const float*)d_in[l];
  const float* att   = (const float*)d_in[5];
  const float* ktw   = (const float*)d_in[6];
  const float* ktb   = (const float*)d_in[7];
  const float* vtw   = (const float*)d_in[8];
  const float* vtb   = (const float*)d_in[9];
  const float* kqw   = (const float*)d_in[10];
  const float* kqb   = (const float*)d_in[11];
  const float* vqw   = (const float*)d_in[12];
  const float* vqb   = (const float*)d_in[13];
  const float* gamma = (const float*)d_in[14];
  const float* beta  = (const float*)d_in[15];
  const float* cw    = (const float*)d_in[16];
  const float* cbias = (const float*)d_in[17];
  float* out = (float*)d_out;

  // workspace layout (floats)
  float* ws    = (float*)d_ws;
  float* kqall = ws;                     // [30][32][256]        245760
  float* f16v  = ws + 245760;            // [20][128][256]       655360 (vq*10)
  u16*   vt2   = (u16*)(ws + 901120);    // [2][10][128][256]u16 327680 fl
  u16*   cwA   = (u16*)(ws + 1228800);   // [2][256][256] u16    65536 fl
  u16*   cw2A  = (u16*)(ws + 1294336);   // [2][5][256][256]u16  327680 fl
  float* cb    = ws + 1622016;           // [5][256]             1280
  u16*   Xf    = (u16*)(ws + 1623296);   // [21824][512] u16     5586944 fl
  float* S0    = ws + 7210240;           // shared region
  // conv phase:
  u16*   Awv  = (u16*)S0;                  // 3538944 u16 = 1769472 fl
  u16*   Awk  = (u16*)(S0 + 1769472);      //  884736 u16 = 442368 fl
  u16*   Xr   = (u16*)(S0 + 2211840);      // [30][256][512] u16 = 1966080 fl
  u16*   zrow = (u16*)(S0 + 4177920);      // 512 u16 = 256 fl
  // post phases:
  float* aggn    = S0;                     // [200][128][256] = 6553600 fl
  float* g16_all = S0 + 6553600;           // [20][256][256] = 1310720 fl
  u16*   pT      = (u16*)(S0 + 7864320);   // [200][256][256] u16 = 6553600 fl

  // Phase 1: merged preps, then resize + conv
  k_prep1<<<1853, 256, 0, stream>>>(
      feat[0], feat[1], feat[2], feat[3], feat[4], att,
      vqw, vtw, kqw, ktw, cw, gamma, cbias, beta,
      Xf, Xr, Awv, Awk, cwA, cw2A, cb);
  k_prep_xr<<<320, 256, 0, stream>>>(Xf, Xr, zrow);
  k_conv_mfma<<<600, 256, 0, stream>>>(
      Xr, Awv, Awk, zrow, kqall, vt2, f16v, vqb, vtb, kqb, ktb);

  // Phase 2: p + aggn (compute)
  k_pagg<<<1600, 256, 0, stream>>>(kqall, vt2, pT, aggn);

  // Phase 3: g16, then fused fa-expansion + final-combine (overlapped pipes)
  k_g16f<<<640, 256, 0, stream>>>(f16v, aggn, cw2A, g16_all);
  k_combo<<<8656, 256, 0, stream>>>(pT, cwA, Xf, g16_all, cb, out);
}